// Round 1
// baseline (245.627 us; speedup 1.0000x reference)
//
#include <hip/hip_runtime.h>
#include <math.h>

namespace {
constexpr int IN_FEATS = 768;
constexpr int HIDDEN   = 128;
constexpr int G        = 1024;
constexpr int NPG      = 256;   // nodes per graph
constexpr int NCHUNK   = 4;     // row chunks per graph for the sum kernel
constexpr int ROWS     = NPG / NCHUNK;  // 64
constexpr int C4       = IN_FEATS / 4;  // 192 float4 columns
}

// ---------------------------------------------------------------------------
// Kernel 0: graph-independent constants.
//  cbuf[0..127]   = C1   = ainv*(hc0+hc1) + hp/259 + b1        (h1_prompt const part)
//  cbuf[128..255] = D0   = 0.5*(relu(ainv*hp+0.5*hc0+b1)@W2) + b2
//  cbuf[256..383] = D1   = 0.5*(relu(ainv*hp+0.5*hc1+b1)@W2) + b2
// where hp = prompt@W1, hck = class_nodes[k]@W1, ainv = 1/sqrt(518).
// ---------------------------------------------------------------------------
__global__ __launch_bounds__(HIDDEN) void const_kernel(
    const float* __restrict__ prompt, const float* __restrict__ cls,
    const float* __restrict__ W1, const float* __restrict__ b1,
    const float* __restrict__ W2, const float* __restrict__ b2,
    float* __restrict__ cbuf) {
    __shared__ float rc0[HIDDEN];
    __shared__ float rc1[HIDDEN];
    const int j = threadIdx.x;
    float hp = 0.f, h0 = 0.f, h1 = 0.f;
    #pragma unroll 8
    for (int c = 0; c < IN_FEATS; ++c) {
        const float w = W1[c * HIDDEN + j];
        hp = fmaf(prompt[c], w, hp);
        h0 = fmaf(cls[c], w, h0);
        h1 = fmaf(cls[IN_FEATS + c], w, h1);
    }
    const float ainv = 1.0f / sqrtf(518.0f);   // edge norm: dinv_prompt * dinv_other
    const float b = b1[j];
    cbuf[j] = ainv * (h0 + h1) + hp * (1.0f / 259.0f) + b;
    rc0[j] = fmaxf(fmaf(ainv, hp, fmaf(0.5f, h0, b)), 0.0f);
    rc1[j] = fmaxf(fmaf(ainv, hp, fmaf(0.5f, h1, b)), 0.0f);
    __syncthreads();
    float u0 = 0.f, u1 = 0.f;
    #pragma unroll 8
    for (int c = 0; c < HIDDEN; ++c) {
        const float w = W2[c * HIDDEN + j];
        u0 = fmaf(rc0[c], w, u0);
        u1 = fmaf(rc1[c], w, u1);
    }
    const float bb = b2[j];
    cbuf[HIDDEN + j]     = fmaf(0.5f, u0, bb);
    cbuf[2 * HIDDEN + j] = fmaf(0.5f, u1, bb);
}

// ---------------------------------------------------------------------------
// Kernel 1: per-graph column sums of x (the only heavy memory op, 805 MB read).
// partial[chunk][g][c] = sum over 64 rows of the chunk.
// ---------------------------------------------------------------------------
__global__ __launch_bounds__(C4) void graph_sum_kernel(
    const float* __restrict__ x, float* __restrict__ partial) {
    const int g = blockIdx.x;
    const int chunk = blockIdx.y;
    const int t = threadIdx.x;  // 0..191, one float4 column each
    const float4* xp = reinterpret_cast<const float4*>(x) +
                       (size_t)(g * NPG + chunk * ROWS) * C4 + t;
    float4 a0 = make_float4(0.f, 0.f, 0.f, 0.f);
    float4 a1 = a0, a2 = a0, a3 = a0;
    for (int r = 0; r < ROWS; r += 4) {
        const float4 v0 = xp[(size_t)(r + 0) * C4];
        const float4 v1 = xp[(size_t)(r + 1) * C4];
        const float4 v2 = xp[(size_t)(r + 2) * C4];
        const float4 v3 = xp[(size_t)(r + 3) * C4];
        a0.x += v0.x; a0.y += v0.y; a0.z += v0.z; a0.w += v0.w;
        a1.x += v1.x; a1.y += v1.y; a1.z += v1.z; a1.w += v1.w;
        a2.x += v2.x; a2.y += v2.y; a2.z += v2.z; a2.w += v2.w;
        a3.x += v3.x; a3.y += v3.y; a3.z += v3.z; a3.w += v3.w;
    }
    float4 s;
    s.x = (a0.x + a1.x) + (a2.x + a3.x);
    s.y = (a0.y + a1.y) + (a2.y + a3.y);
    s.z = (a0.z + a1.z) + (a2.z + a3.z);
    s.w = (a0.w + a1.w) + (a2.w + a3.w);
    reinterpret_cast<float4*>(partial)[((size_t)chunk * G + g) * C4 + t] = s;
}

// ---------------------------------------------------------------------------
// Kernel 2: per-graph head.
//  S_g = sum of partials; t = S_g@W1; h1p = ainv*t + C1; r = relu(h1p);
//  u = r@W2; for k: v = ainv*u + Dk; logits = v@Wfc + bfc; log_softmax.
// ---------------------------------------------------------------------------
__global__ __launch_bounds__(HIDDEN) void head_kernel(
    const float* __restrict__ partial,
    const float* __restrict__ W1, const float* __restrict__ W2,
    const float* __restrict__ Wfc, const float* __restrict__ bfc,
    const float* __restrict__ cbuf, float* __restrict__ out) {
    __shared__ float S[IN_FEATS];
    __shared__ float r[HIDDEN];
    __shared__ float red[2][2];
    const int g = blockIdx.x;
    const int j = threadIdx.x;  // 0..127

    // reduce the 4 partial chunks into S
    for (int c = j; c < IN_FEATS; c += HIDDEN) {
        float s = 0.f;
        #pragma unroll
        for (int p = 0; p < NCHUNK; ++p)
            s += partial[((size_t)p * G + g) * IN_FEATS + c];
        S[c] = s;
    }
    __syncthreads();

    // t_j = S . W1[:, j]
    float t = 0.f;
    #pragma unroll 8
    for (int c = 0; c < IN_FEATS; ++c)
        t = fmaf(S[c], W1[c * HIDDEN + j], t);

    const float ainv = 1.0f / sqrtf(518.0f);
    r[j] = fmaxf(fmaf(ainv, t, cbuf[j]), 0.0f);
    __syncthreads();

    // u_j = r . W2[:, j]
    float u = 0.f;
    #pragma unroll 8
    for (int c = 0; c < HIDDEN; ++c)
        u = fmaf(r[c], W2[c * HIDDEN + j], u);

    const float bfc0 = bfc[0], bfc1 = bfc[1];
    for (int k = 0; k < 2; ++k) {
        const float v = fmaf(ainv, u, cbuf[HIDDEN + k * HIDDEN + j]);
        float p0 = v * Wfc[j * 2 + 0];
        float p1 = v * Wfc[j * 2 + 1];
        #pragma unroll
        for (int off = 32; off > 0; off >>= 1) {
            p0 += __shfl_down(p0, off);
            p1 += __shfl_down(p1, off);
        }
        if ((j & 63) == 0) {
            red[j >> 6][0] = p0;
            red[j >> 6][1] = p1;
        }
        __syncthreads();
        if (j == 0) {
            const float l0 = red[0][0] + red[1][0] + bfc0;
            const float l1 = red[0][1] + red[1][1] + bfc1;
            const float m = fmaxf(l0, l1);
            const float lse = m + logf(expf(l0 - m) + expf(l1 - m));
            float* o = out + ((size_t)g * 2 + k) * 2;
            o[0] = l0 - lse;
            o[1] = l1 - lse;
        }
        __syncthreads();
    }
}

extern "C" void kernel_launch(void* const* d_in, const int* in_sizes, int n_in,
                              void* d_out, int out_size, void* d_ws, size_t ws_size,
                              hipStream_t stream) {
    const float* x      = (const float*)d_in[0];
    const float* prompt = (const float*)d_in[1];
    const float* cls    = (const float*)d_in[2];
    const float* W1     = (const float*)d_in[3];
    const float* b1     = (const float*)d_in[4];
    const float* W2     = (const float*)d_in[5];
    const float* b2     = (const float*)d_in[6];
    const float* Wfc    = (const float*)d_in[7];
    const float* bfc    = (const float*)d_in[8];
    float* out = (float*)d_out;

    float* partial = (float*)d_ws;                                   // 4*1024*768 f32 = 12.6 MB
    float* cbuf    = partial + (size_t)NCHUNK * G * IN_FEATS;        // 384 f32

    const_kernel<<<1, HIDDEN, 0, stream>>>(prompt, cls, W1, b1, W2, b2, cbuf);
    graph_sum_kernel<<<dim3(G, NCHUNK), C4, 0, stream>>>(x, partial);
    head_kernel<<<G, HIDDEN, 0, stream>>>(partial, W1, W2, Wfc, bfc, cbuf, out);
}

// Round 2
// 166.951 us; speedup vs baseline: 1.4712x; 1.4712x over previous
//
#include <hip/hip_runtime.h>
#include <math.h>

namespace {
constexpr int IN_FEATS = 768;
constexpr int HIDDEN   = 128;
constexpr int G        = 1024;
constexpr int NPG      = 256;          // nodes per graph
constexpr int C4       = IN_FEATS / 4; // 192 float4 columns per row
constexpr int NT       = 384;          // 6 waves; 4 blocks/CU -> whole grid co-resident
}

// One block per graph. Phases:
//  A: sum 256 rows of x (768 cols) -> S[768] in LDS           (the 805 MB HBM read)
//  B: t = S@W1, and (redundantly per block, but load-bound so free)
//     hp = prompt@W1, h0/h1 = class@W1; 3 c-segments x 128 j-threads
//  C: r = relu(ainv*t + C1); rc_k = relu(ainv*hp + 0.5*h_k + b1);
//     u = r@W2, u_k = rc_k@W2 (shared W2 loads)
//  D: v_k = ainv*u + 0.5*u_k + b2; logits = v_k@Wfc + bfc; log_softmax
// Derivation (verified exact in R0): deg(orig)=2, deg(prompt)=259, deg(class)=2;
// ainv = 1/sqrt(518) edge norm; prompt self-loop 1/259; class/orig self-loop 1/2.
__global__ __launch_bounds__(NT, 6) void fused_kernel(
    const float* __restrict__ x, const float* __restrict__ prompt,
    const float* __restrict__ cls,
    const float* __restrict__ W1, const float* __restrict__ b1,
    const float* __restrict__ W2, const float* __restrict__ b2,
    const float* __restrict__ Wfc, const float* __restrict__ bfc,
    float* __restrict__ out)
{
    __shared__ float   S[IN_FEATS];        // 3 KB   graph column-sum
    __shared__ float   pc[3 * IN_FEATS];   // 9 KB   prompt | cls0 | cls1
    __shared__ float4  partA[2][C4];       // 6 KB   phase-A row-parity partials
    __shared__ float4  pb[3][HIDDEN];      // 6 KB   phase-B segment partials (t,hp,h0,h1)
    __shared__ float   rbuf[3][HIDDEN];    // 1.5 KB r, rc0, rc1
    __shared__ float   red[2][2];

    const int g   = blockIdx.x;
    const int tid = threadIdx.x;
    const float ainv = 1.0f / sqrtf(518.0f);

    // stage prompt + class rows into LDS (2304 floats)
    for (int i = tid; i < 3 * IN_FEATS; i += NT)
        pc[i] = (i < IN_FEATS) ? prompt[i] : cls[i - IN_FEATS];

    // ---- Phase A: per-graph column sum of x ------------------------------
    const int p  = tid / C4;   // row parity 0/1
    const int c4 = tid % C4;   // float4 column
    const float4* xp = reinterpret_cast<const float4*>(x) +
                       ((size_t)g * NPG + p) * C4 + c4;
    float4 a0 = make_float4(0.f, 0.f, 0.f, 0.f);
    float4 a1 = a0, a2 = a0, a3 = a0;
    for (int i = 0; i < NPG / 2; i += 4) {
        const float4 v0 = xp[(size_t)(2 * (i + 0)) * C4];
        const float4 v1 = xp[(size_t)(2 * (i + 1)) * C4];
        const float4 v2 = xp[(size_t)(2 * (i + 2)) * C4];
        const float4 v3 = xp[(size_t)(2 * (i + 3)) * C4];
        a0.x += v0.x; a0.y += v0.y; a0.z += v0.z; a0.w += v0.w;
        a1.x += v1.x; a1.y += v1.y; a1.z += v1.z; a1.w += v1.w;
        a2.x += v2.x; a2.y += v2.y; a2.z += v2.z; a2.w += v2.w;
        a3.x += v3.x; a3.y += v3.y; a3.z += v3.z; a3.w += v3.w;
    }
    float4 s;
    s.x = (a0.x + a1.x) + (a2.x + a3.x);
    s.y = (a0.y + a1.y) + (a2.y + a3.y);
    s.z = (a0.z + a1.z) + (a2.z + a3.z);
    s.w = (a0.w + a1.w) + (a2.w + a3.w);
    partA[p][c4] = s;
    __syncthreads();
    if (tid < C4) {
        const float4 q0 = partA[0][tid], q1 = partA[1][tid];
        reinterpret_cast<float4*>(S)[tid] =
            make_float4(q0.x + q1.x, q0.y + q1.y, q0.z + q1.z, q0.w + q1.w);
    }
    __syncthreads();

    // ---- Phase B: four 768->128 matvecs sharing each W1 load -------------
    {
        const int seg = tid >> 7;          // 0..2  (c-range of 256)
        const int j   = tid & (HIDDEN - 1);
        const int cb  = seg * 256;
        const float* w1p = W1 + (size_t)cb * HIDDEN + j;
        float t = 0.f, hp = 0.f, h0 = 0.f, h1 = 0.f;
        #pragma unroll 4
        for (int cc = 0; cc < 256; ++cc) {
            const float w = w1p[(size_t)cc * HIDDEN];
            const int  c = cb + cc;
            t  = fmaf(S[c], w, t);
            hp = fmaf(pc[c], w, hp);
            h0 = fmaf(pc[IN_FEATS + c], w, h0);
            h1 = fmaf(pc[2 * IN_FEATS + c], w, h1);
        }
        pb[seg][j] = make_float4(t, hp, h0, h1);
    }
    __syncthreads();
    if (tid < HIDDEN) {
        const float4 q0 = pb[0][tid], q1 = pb[1][tid], q2 = pb[2][tid];
        const float t  = (q0.x + q1.x) + q2.x;
        const float hp = (q0.y + q1.y) + q2.y;
        const float h0 = (q0.z + q1.z) + q2.z;
        const float h1 = (q0.w + q1.w) + q2.w;
        const float b  = b1[tid];
        const float C1 = ainv * (h0 + h1) + hp * (1.0f / 259.0f) + b;
        rbuf[0][tid] = fmaxf(fmaf(ainv, t, C1), 0.f);                    // r
        rbuf[1][tid] = fmaxf(fmaf(ainv, hp, fmaf(0.5f, h0, b)), 0.f);    // rc0
        rbuf[2][tid] = fmaxf(fmaf(ainv, hp, fmaf(0.5f, h1, b)), 0.f);    // rc1
    }
    __syncthreads();

    // ---- Phase C: three 128->128 matvecs sharing each W2 load ------------
    float u = 0.f, u0 = 0.f, u1 = 0.f;
    if (tid < HIDDEN) {
        const float* w2p = W2 + tid;
        #pragma unroll 4
        for (int c = 0; c < HIDDEN; ++c) {
            const float w = w2p[(size_t)c * HIDDEN];
            u  = fmaf(rbuf[0][c], w, u);
            u0 = fmaf(rbuf[1][c], w, u0);
            u1 = fmaf(rbuf[2][c], w, u1);
        }
    }

    // ---- Phase D: logits + log_softmax -----------------------------------
    const float bfc0 = bfc[0], bfc1 = bfc[1];
    for (int k = 0; k < 2; ++k) {
        float p0 = 0.f, p1 = 0.f;
        if (tid < HIDDEN) {
            const float uk = (k == 0) ? u0 : u1;
            const float v  = fmaf(ainv, u, fmaf(0.5f, uk, b2[tid]));
            p0 = v * Wfc[tid * 2 + 0];
            p1 = v * Wfc[tid * 2 + 1];
            #pragma unroll
            for (int off = 32; off > 0; off >>= 1) {
                p0 += __shfl_down(p0, off);
                p1 += __shfl_down(p1, off);
            }
            if ((tid & 63) == 0) { red[tid >> 6][0] = p0; red[tid >> 6][1] = p1; }
        }
        __syncthreads();
        if (tid == 0) {
            const float l0 = red[0][0] + red[1][0] + bfc0;
            const float l1 = red[0][1] + red[1][1] + bfc1;
            const float m   = fmaxf(l0, l1);
            const float lse = m + logf(expf(l0 - m) + expf(l1 - m));
            float* o = out + ((size_t)g * 2 + k) * 2;
            o[0] = l0 - lse;
            o[1] = l1 - lse;
        }
        __syncthreads();
    }
}

extern "C" void kernel_launch(void* const* d_in, const int* in_sizes, int n_in,
                              void* d_out, int out_size, void* d_ws, size_t ws_size,
                              hipStream_t stream) {
    const float* x      = (const float*)d_in[0];
    const float* prompt = (const float*)d_in[1];
    const float* cls    = (const float*)d_in[2];
    const float* W1     = (const float*)d_in[3];
    const float* b1     = (const float*)d_in[4];
    const float* W2     = (const float*)d_in[5];
    const float* b2     = (const float*)d_in[6];
    const float* Wfc    = (const float*)d_in[7];
    const float* bfc    = (const float*)d_in[8];
    float* out = (float*)d_out;

    fused_kernel<<<G, NT, 0, stream>>>(x, prompt, cls, W1, b1, W2, b2,
                                       Wfc, bfc, out);
}

// Round 4
// 145.484 us; speedup vs baseline: 1.6883x; 1.1476x over previous
//
#include <hip/hip_runtime.h>
#include <math.h>

namespace {
constexpr int IN_FEATS = 768;
constexpr int HIDDEN   = 128;
constexpr int G        = 1024;
constexpr int NPG      = 256;          // nodes per graph
constexpr int C4       = IN_FEATS / 4; // 192 float4 columns per row
constexpr int NT       = 384;          // 6 waves
constexpr int GPB      = 2;            // graphs per block
constexpr int NB       = G / GPB;      // 512 blocks
typedef float f32x4 __attribute__((ext_vector_type(4)));  // nontemporal-compatible
}

// One block per 2 graphs. Exact closed form of the reference (verified R0/R1):
//   deg(orig)=2, deg(prompt)=259, deg(class)=2; ainv = 1/sqrt(518)
//   r_g   = relu(ainv*(S_g@W1) + ainv*(h0+h1) + hp/259 + b1)
//   rc_k  = relu(ainv*hp + 0.5*h_k + b1)
//   v_gk  = ainv*(r_g@W2) + 0.5*(rc_k@W2) + b2
//   out   = log_softmax(v_gk @ Wfc + bfc)
// where S_g = column-sum of graph g's 256 rows, hp = prompt@W1, h_k = class_k@W1.
// hp/h0/h1 are recomputed per block: they ride on the same W1 loads as t (load-bound).
__global__ __launch_bounds__(NT, 3) void fused_kernel(
    const float* __restrict__ x, const float* __restrict__ prompt,
    const float* __restrict__ cls,
    const float* __restrict__ W1, const float* __restrict__ b1,
    const float* __restrict__ W2, const float* __restrict__ b2,
    const float* __restrict__ Wfc, const float* __restrict__ bfc,
    float* __restrict__ out)
{
    __shared__ __align__(16) float S[GPB][IN_FEATS];   // 6 KB graph column-sums
    __shared__ f32x4  partA[2][C4];                    // 6 KB phase-A parity partials
    __shared__ float  pb[3][5][HIDDEN];                // 7.5 KB phase-B seg partials
    __shared__ __align__(16) float rbuf[4][HIDDEN];    // 2 KB r0,r1,rc0,rc1
    __shared__ float  red[2][2];

    const int g0  = blockIdx.x * GPB;
    const int tid = threadIdx.x;
    const float ainv = 1.0f / sqrtf(518.0f);

    // ---- Phase A: per-graph column sums (the 805 MB HBM read) ------------
    const int p  = tid / C4;   // row parity 0/1
    const int c4 = tid % C4;   // float4 column
    const f32x4* xb = reinterpret_cast<const f32x4*>(x);
    for (int gg = 0; gg < GPB; ++gg) {
        const f32x4* xp = xb + ((size_t)(g0 + gg) * NPG + p) * C4 + c4;
        f32x4 a0 = (f32x4)0.0f;
        f32x4 a1 = a0, a2 = a0, a3 = a0;
        for (int i = 0; i < NPG / 2; i += 4) {
            const f32x4 v0 = __builtin_nontemporal_load(xp + (size_t)(2 * (i + 0)) * C4);
            const f32x4 v1 = __builtin_nontemporal_load(xp + (size_t)(2 * (i + 1)) * C4);
            const f32x4 v2 = __builtin_nontemporal_load(xp + (size_t)(2 * (i + 2)) * C4);
            const f32x4 v3 = __builtin_nontemporal_load(xp + (size_t)(2 * (i + 3)) * C4);
            a0 += v0; a1 += v1; a2 += v2; a3 += v3;
        }
        partA[p][c4] = (a0 + a1) + (a2 + a3);
        __syncthreads();
        if (tid < C4) {
            const f32x4 q0 = partA[0][tid], q1 = partA[1][tid];
            *reinterpret_cast<f32x4*>(&S[gg][tid * 4]) = q0 + q1;
        }
        __syncthreads();
    }

    // ---- Phase B: five 768->128 matvecs sharing each W1 load -------------
    {
        const int seg = tid >> 7;          // 0..2, c-range of 256
        const int j   = tid & (HIDDEN - 1);
        const int cb  = seg * 256;
        const float* w1p = W1 + (size_t)cb * HIDDEN + j;
        float t0 = 0.f, t1 = 0.f, hp = 0.f, h0 = 0.f, h1 = 0.f;
        for (int cc = 0; cc < 256; cc += 4) {
            const int c = cb + cc;
            const f32x4 s0 = *reinterpret_cast<const f32x4*>(&S[0][c]); // ds_read_b128
            const f32x4 s1 = *reinterpret_cast<const f32x4*>(&S[1][c]);
            const f32x4 pv = *reinterpret_cast<const f32x4*>(prompt + c);      // uniform
            const f32x4 k0 = *reinterpret_cast<const f32x4*>(cls + c);         // uniform
            const f32x4 k1 = *reinterpret_cast<const f32x4*>(cls + IN_FEATS + c);
            const float w0 = w1p[(size_t)(cc + 0) * HIDDEN];
            const float w1 = w1p[(size_t)(cc + 1) * HIDDEN];
            const float w2 = w1p[(size_t)(cc + 2) * HIDDEN];
            const float w3 = w1p[(size_t)(cc + 3) * HIDDEN];
            t0 = fmaf(s0.x, w0, t0); t1 = fmaf(s1.x, w0, t1);
            hp = fmaf(pv.x, w0, hp); h0 = fmaf(k0.x, w0, h0); h1 = fmaf(k1.x, w0, h1);
            t0 = fmaf(s0.y, w1, t0); t1 = fmaf(s1.y, w1, t1);
            hp = fmaf(pv.y, w1, hp); h0 = fmaf(k0.y, w1, h0); h1 = fmaf(k1.y, w1, h1);
            t0 = fmaf(s0.z, w2, t0); t1 = fmaf(s1.z, w2, t1);
            hp = fmaf(pv.z, w2, hp); h0 = fmaf(k0.z, w2, h0); h1 = fmaf(k1.z, w2, h1);
            t0 = fmaf(s0.w, w3, t0); t1 = fmaf(s1.w, w3, t1);
            hp = fmaf(pv.w, w3, hp); h0 = fmaf(k0.w, w3, h0); h1 = fmaf(k1.w, w3, h1);
        }
        pb[seg][0][j] = t0; pb[seg][1][j] = t1;
        pb[seg][2][j] = hp; pb[seg][3][j] = h0; pb[seg][4][j] = h1;
    }
    __syncthreads();
    if (tid < HIDDEN) {
        const float t0 = pb[0][0][tid] + pb[1][0][tid] + pb[2][0][tid];
        const float t1 = pb[0][1][tid] + pb[1][1][tid] + pb[2][1][tid];
        const float hp = pb[0][2][tid] + pb[1][2][tid] + pb[2][2][tid];
        const float h0 = pb[0][3][tid] + pb[1][3][tid] + pb[2][3][tid];
        const float h1 = pb[0][4][tid] + pb[1][4][tid] + pb[2][4][tid];
        const float b  = b1[tid];
        const float C1 = ainv * (h0 + h1) + hp * (1.0f / 259.0f) + b;
        rbuf[0][tid] = fmaxf(fmaf(ainv, t0, C1), 0.f);                  // r_g0
        rbuf[1][tid] = fmaxf(fmaf(ainv, t1, C1), 0.f);                  // r_g1
        rbuf[2][tid] = fmaxf(fmaf(ainv, hp, fmaf(0.5f, h0, b)), 0.f);   // rc0
        rbuf[3][tid] = fmaxf(fmaf(ainv, hp, fmaf(0.5f, h1, b)), 0.f);   // rc1
    }
    __syncthreads();

    // ---- Phase C: four 128->128 matvecs sharing each W2 load -------------
    float u0 = 0.f, u1 = 0.f, uc0 = 0.f, uc1 = 0.f;
    if (tid < HIDDEN) {
        const float* w2p = W2 + tid;
        for (int c = 0; c < HIDDEN; c += 4) {
            const f32x4 r0 = *reinterpret_cast<const f32x4*>(&rbuf[0][c]);
            const f32x4 r1 = *reinterpret_cast<const f32x4*>(&rbuf[1][c]);
            const f32x4 q0 = *reinterpret_cast<const f32x4*>(&rbuf[2][c]);
            const f32x4 q1 = *reinterpret_cast<const f32x4*>(&rbuf[3][c]);
            const float wa = w2p[(size_t)(c + 0) * HIDDEN];
            const float wb = w2p[(size_t)(c + 1) * HIDDEN];
            const float wc = w2p[(size_t)(c + 2) * HIDDEN];
            const float wd = w2p[(size_t)(c + 3) * HIDDEN];
            u0  = fmaf(r0.x, wa, u0);  u1  = fmaf(r1.x, wa, u1);
            uc0 = fmaf(q0.x, wa, uc0); uc1 = fmaf(q1.x, wa, uc1);
            u0  = fmaf(r0.y, wb, u0);  u1  = fmaf(r1.y, wb, u1);
            uc0 = fmaf(q0.y, wb, uc0); uc1 = fmaf(q1.y, wb, uc1);
            u0  = fmaf(r0.z, wc, u0);  u1  = fmaf(r1.z, wc, u1);
            uc0 = fmaf(q0.z, wc, uc0); uc1 = fmaf(q1.z, wc, uc1);
            u0  = fmaf(r0.w, wd, u0);  u1  = fmaf(r1.w, wd, u1);
            uc0 = fmaf(q0.w, wd, uc0); uc1 = fmaf(q1.w, wd, uc1);
        }
    }

    // ---- Phase D: logits + log_softmax per (graph, class) ----------------
    const float bfc0 = bfc[0], bfc1 = bfc[1];
    for (int gg = 0; gg < GPB; ++gg) {
        for (int k = 0; k < 2; ++k) {
            float p0 = 0.f, p1 = 0.f;
            if (tid < HIDDEN) {
                const float ug = (gg == 0) ? u0 : u1;
                const float uk = (k == 0) ? uc0 : uc1;
                const float v  = fmaf(ainv, ug, fmaf(0.5f, uk, b2[tid]));
                p0 = v * Wfc[tid * 2 + 0];
                p1 = v * Wfc[tid * 2 + 1];
                #pragma unroll
                for (int off = 32; off > 0; off >>= 1) {
                    p0 += __shfl_down(p0, off);
                    p1 += __shfl_down(p1, off);
                }
                if ((tid & 63) == 0) { red[tid >> 6][0] = p0; red[tid >> 6][1] = p1; }
            }
            __syncthreads();
            if (tid == 0) {
                const float l0 = red[0][0] + red[1][0] + bfc0;
                const float l1 = red[0][1] + red[1][1] + bfc1;
                const float m   = fmaxf(l0, l1);
                const float lse = m + logf(expf(l0 - m) + expf(l1 - m));
                float* o = out + ((size_t)(g0 + gg) * 2 + k) * 2;
                o[0] = l0 - lse;
                o[1] = l1 - lse;
            }
            __syncthreads();
        }
    }
}

extern "C" void kernel_launch(void* const* d_in, const int* in_sizes, int n_in,
                              void* d_out, int out_size, void* d_ws, size_t ws_size,
                              hipStream_t stream) {
    const float* x      = (const float*)d_in[0];
    const float* prompt = (const float*)d_in[1];
    const float* cls    = (const float*)d_in[2];
    const float* W1     = (const float*)d_in[3];
    const float* b1     = (const float*)d_in[4];
    const float* W2     = (const float*)d_in[5];
    const float* b2     = (const float*)d_in[6];
    const float* Wfc    = (const float*)d_in[7];
    const float* bfc    = (const float*)d_in[8];
    float* out = (float*)d_out;

    fused_kernel<<<NB, NT, 0, stream>>>(x, prompt, cls, W1, b1, W2, b2,
                                        Wfc, bfc, out);
}